// Round 1
// baseline (340.677 us; speedup 1.0000x reference)
//
#include <hip/hip_runtime.h>
#include <hip/hip_bf16.h>

typedef __bf16 bf16_t;
typedef __bf16 bf16x8 __attribute__((ext_vector_type(8)));
typedef __bf16 bf16x4 __attribute__((ext_vector_type(4)));
typedef float f32x4 __attribute__((ext_vector_type(4)));

#define LDS_AS __attribute__((address_space(3)))
#define GLB_AS __attribute__((address_space(1)))

__device__ __forceinline__ void gload_lds16(const void* g, void* l) {
  __builtin_amdgcn_global_load_lds((const GLB_AS void*)g, (LDS_AS void*)l, 16, 0, 0);
}

static __device__ __forceinline__ f32x4 mfma16(bf16x8 a, bf16x8 b, f32x4 c) {
  return __builtin_amdgcn_mfma_f32_16x16x32_bf16(a, b, c, 0, 0, 0);
}

// ---------------------------------------------------------------- cast fp32 -> bf16
// x (8388608) + wq,wk,wv,wo (1048576 each). 4 elems/thread, exact grid.
__global__ __launch_bounds__(256) void cast_kernel(
    const float* __restrict__ x, const float* __restrict__ wq,
    const float* __restrict__ wk, const float* __restrict__ wv,
    const float* __restrict__ wo, bf16_t* __restrict__ xb,
    bf16_t* __restrict__ wqb, bf16_t* __restrict__ wkb,
    bf16_t* __restrict__ wvb, bf16_t* __restrict__ wob) {
  size_t i = ((size_t)blockIdx.x * 256 + threadIdx.x) * 4;
  const float* s;
  bf16_t* d;
  size_t off;
  if (i < 8388608) {
    s = x; d = xb; off = i;
  } else {
    size_t j = i - 8388608;
    int wi = (int)(j >> 20);
    off = j & 1048575;
    s = wi == 0 ? wq : wi == 1 ? wk : wi == 2 ? wv : wo;
    d = wi == 0 ? wqb : wi == 1 ? wkb : wi == 2 ? wvb : wob;
  }
  float4 v = *(const float4*)(s + off);
  bf16x4 o;
  o[0] = (bf16_t)v.x; o[1] = (bf16_t)v.y; o[2] = (bf16_t)v.z; o[3] = (bf16_t)v.w;
  *(bf16x4*)(d + off) = o;
}

// ---------------------------------------------------------------- GEMM mainloop (m97 structure)
// C[m][n] = sum_k A[m][k] * W[n][k]   (A: [8192][1024] bf16, W: [1024][1024] bf16)
// 128x128 tile, BK=32, 4 waves (2x2 of 64x64), global_load_lds width=16, linear LDS.
__device__ __forceinline__ void gemm_loop(const bf16_t* __restrict__ A,
                                          const bf16_t* __restrict__ W,
                                          bf16_t* lA, bf16_t* lB, int rowBase,
                                          int colBase, int tid,
                                          f32x4 (&acc)[4][4]) {
  const int lane = tid & 63, w = tid >> 6;
  const int lhi = lane >> 4, llo = lane & 15;
  const int wr = w >> 1, wc = w & 1;
  const int cBase = w * 64 + lane;  // chunk index (16B chunks), i adds 256
  for (int kt = 0; kt < 32; ++kt) {
    __syncthreads();  // previous iter's reads done before overwrite
#pragma unroll
    for (int i = 0; i < 2; ++i) {
      int c = i * 256 + cBase;  // 0..511 ; row=c>>2 (64B rows), kc=c&3
      gload_lds16(A + (size_t)(rowBase + (c >> 2)) * 1024 + kt * 32 + (c & 3) * 8,
                  lA + (size_t)(i * 256 + w * 64) * 8);
      gload_lds16(W + (size_t)(colBase + (c >> 2)) * 1024 + kt * 32 + (c & 3) * 8,
                  lB + (size_t)(i * 256 + w * 64) * 8);
    }
    __syncthreads();  // drains vmcnt: LDS tiles ready
    bf16x8 aF[4], bF[4];
#pragma unroll
    for (int i = 0; i < 4; ++i)
      aF[i] = *(const bf16x8*)&lA[(wr * 64 + i * 16 + llo) * 32 + lhi * 8];
#pragma unroll
    for (int j = 0; j < 4; ++j)
      bF[j] = *(const bf16x8*)&lB[(wc * 64 + j * 16 + llo) * 32 + lhi * 8];
#pragma unroll
    for (int i = 0; i < 4; ++i)
#pragma unroll
      for (int j = 0; j < 4; ++j) acc[i][j] = mfma16(aF[i], bF[j], acc[i][j]);
  }
}

// ---------------------------------------------------------------- QKV projection
// grid (64, 8, 3): z=0 Q (bf16 [b,h,t,d]), z=1 K (fp32 out + bf16 [b,h,t,d]),
// z=2 V (fp32 out + bf16 V^T [b,h,d,t]).
__global__ __launch_bounds__(256) void gemm_qkv(
    const bf16_t* __restrict__ xb, const bf16_t* __restrict__ wqb,
    const bf16_t* __restrict__ wkb, const bf16_t* __restrict__ wvb,
    bf16_t* __restrict__ Qb, bf16_t* __restrict__ Kb, bf16_t* __restrict__ vTb,
    float* __restrict__ outK, float* __restrict__ outV) {
  __shared__ bf16_t lA[128 * 32];
  __shared__ bf16_t lB[128 * 32];
  const int tid = threadIdx.x;
  const int mode = blockIdx.z;
  const bf16_t* W = mode == 0 ? wqb : (mode == 1 ? wkb : wvb);
  const int rowBase = blockIdx.x * 128, colBase = blockIdx.y * 128;
  f32x4 acc[4][4] = {};
  gemm_loop(xb, W, lA, lB, rowBase, colBase, tid, acc);
  const int lane = tid & 63, w = tid >> 6;
  const int lhi = lane >> 4, llo = lane & 15;
  const int wr = w >> 1, wc = w & 1;
#pragma unroll
  for (int i = 0; i < 4; ++i) {
    int m0 = rowBase + wr * 64 + i * 16 + lhi * 4;  // +r
    int b = m0 >> 11;
    int tok0 = m0 & 2047;
#pragma unroll
    for (int j = 0; j < 4; ++j) {
      int n = colBase + wc * 64 + j * 16 + llo;
      int h = n >> 6, dk = n & 63;
      size_t hoff = ((size_t)(b * 16 + h) * 2048 + tok0) * 64 + dk;
      if (mode == 0) {
#pragma unroll
        for (int r = 0; r < 4; ++r) Qb[hoff + (size_t)r * 64] = (bf16_t)acc[i][j][r];
      } else if (mode == 1) {
#pragma unroll
        for (int r = 0; r < 4; ++r) {
          outK[hoff + (size_t)r * 64] = acc[i][j][r];
          Kb[hoff + (size_t)r * 64] = (bf16_t)acc[i][j][r];
        }
      } else {
#pragma unroll
        for (int r = 0; r < 4; ++r) outV[hoff + (size_t)r * 64] = acc[i][j][r];
        bf16x4 pk;
#pragma unroll
        for (int r = 0; r < 4; ++r) pk[r] = (bf16_t)acc[i][j][r];
        // V^T: 4 consecutive tokens at fixed dk -> one 8B store
        *(bf16x4*)&vTb[((size_t)(b * 16 + h) * 64 + dk) * 2048 + tok0] = pk;
      }
    }
  }
}

// ---------------------------------------------------------------- output projection
__global__ __launch_bounds__(256) void gemm_out(const bf16_t* __restrict__ valsb,
                                                const bf16_t* __restrict__ wob,
                                                float* __restrict__ out) {
  __shared__ bf16_t lA[128 * 32];
  __shared__ bf16_t lB[128 * 32];
  const int tid = threadIdx.x;
  const int rowBase = blockIdx.x * 128, colBase = blockIdx.y * 128;
  f32x4 acc[4][4] = {};
  gemm_loop(valsb, wob, lA, lB, rowBase, colBase, tid, acc);
  const int lane = tid & 63, w = tid >> 6;
  const int lhi = lane >> 4, llo = lane & 15;
  const int wr = w >> 1, wc = w & 1;
#pragma unroll
  for (int i = 0; i < 4; ++i) {
    int m0 = rowBase + wr * 64 + i * 16 + lhi * 4;
#pragma unroll
    for (int j = 0; j < 4; ++j) {
      int n = colBase + wc * 64 + j * 16 + llo;
#pragma unroll
      for (int r = 0; r < 4; ++r) out[(size_t)(m0 + r) * 1024 + n] = acc[i][j][r];
    }
  }
}

// ---------------------------------------------------------------- flash attention (causal)
// grid (32 qtiles, 64 heads), 256 thr = 4 waves; wave w owns q-rows [w*16, w*16+16).
// K tile [64 tok][64 dk] and V^T tile [64 dk][64 tok] staged via global_load_lds with
// pre-swizzled global source (chunk ^= row&7) so ds_read_b128 is ~conflict-free.
__global__ __launch_bounds__(256) void attn_kernel(const bf16_t* __restrict__ Qb,
                                                   const bf16_t* __restrict__ Kb,
                                                   const bf16_t* __restrict__ vTb,
                                                   bf16_t* __restrict__ valsb) {
  __shared__ bf16_t kT[64 * 64];
  __shared__ bf16_t vS[64 * 64];
  __shared__ bf16_t pS[4][16 * 72];  // stride 72 elems = 144B (16B-aligned, conflict-free)
  const int tid = threadIdx.x;
  const int lane = tid & 63, w = tid >> 6;
  const int lhi = lane >> 4, llo = lane & 15;
  const int qt = blockIdx.x, head = blockIdx.y;
  const int qbase = qt * 64;
  const bf16_t* Qh = Qb + (size_t)head * 2048 * 64;
  const bf16_t* Kh = Kb + (size_t)head * 2048 * 64;
  const bf16_t* Vh = vTb + (size_t)head * 64 * 2048;
  bf16x8 qF[2];
#pragma unroll
  for (int kk = 0; kk < 2; ++kk)
    qF[kk] = *(const bf16x8*)&Qh[(size_t)(qbase + w * 16 + llo) * 64 + kk * 32 + lhi * 8];
  f32x4 oacc[4] = {};
  float mrow[4], lrow[4];
#pragma unroll
  for (int r = 0; r < 4; ++r) { mrow[r] = -__builtin_inff(); lrow[r] = 0.f; }
  const int cBase = w * 64 + lane;
  for (int kt = 0; kt <= qt; ++kt) {
    const int kbase = kt * 64;
    __syncthreads();
#pragma unroll
    for (int i = 0; i < 2; ++i) {
      int c = i * 256 + cBase;      // 0..511 ; row=c>>3 (128B rows), slot=c&7
      int row = c >> 3, sl = c & 7;
      int src = sl ^ (row & 7);     // pre-swizzled source chunk
      gload_lds16(Kh + (size_t)(kbase + row) * 64 + src * 8,
                  kT + (size_t)(i * 256 + w * 64) * 8);
      gload_lds16(Vh + (size_t)row * 2048 + kbase + src * 8,
                  vS + (size_t)(i * 256 + w * 64) * 8);
    }
    __syncthreads();
    // S = Q K^T
    f32x4 s[4] = {};
#pragma unroll
    for (int kk = 0; kk < 2; ++kk) {
#pragma unroll
      for (int j = 0; j < 4; ++j) {
        int row = j * 16 + llo;
        bf16x8 kf = *(const bf16x8*)&kT[row * 64 + ((kk * 4 + lhi) ^ (row & 7)) * 8];
        s[j] = mfma16(qF[kk], kf, s[j]);
      }
    }
    // scale + causal mask (only diagonal tile needs masking)
    const bool diag = (kt == qt);
#pragma unroll
    for (int j = 0; j < 4; ++j)
#pragma unroll
      for (int r = 0; r < 4; ++r) {
        float v = s[j][r] * 0.125f;
        if (diag && (j * 16 + llo > w * 16 + lhi * 4 + r)) v = -__builtin_inff();
        s[j][r] = v;
      }
    // online softmax, rows r live in 16-lane groups (same lhi)
#pragma unroll
    for (int r = 0; r < 4; ++r) {
      float tm = fmaxf(fmaxf(s[0][r], s[1][r]), fmaxf(s[2][r], s[3][r]));
#pragma unroll
      for (int msk = 1; msk < 16; msk <<= 1) tm = fmaxf(tm, __shfl_xor(tm, msk, 64));
      float mnew = fmaxf(mrow[r], tm);
      float corr = __expf(mrow[r] - mnew);  // exp(-inf)=0 on first tile
      float rs = 0.f;
#pragma unroll
      for (int j = 0; j < 4; ++j) {
        float p = __expf(s[j][r] - mnew);
        s[j][r] = p;
        rs += p;
      }
#pragma unroll
      for (int msk = 1; msk < 16; msk <<= 1) rs += __shfl_xor(rs, msk, 64);
      mrow[r] = mnew;
      lrow[r] = lrow[r] * corr + rs;
#pragma unroll
      for (int nb = 0; nb < 4; ++nb) oacc[nb][r] *= corr;
    }
    // P -> LDS (bf16), per-wave buffer, same-wave RAW (no barrier needed)
#pragma unroll
    for (int j = 0; j < 4; ++j)
#pragma unroll
      for (int r = 0; r < 4; ++r)
        pS[w][(lhi * 4 + r) * 72 + j * 16 + llo] = (bf16_t)s[j][r];
    // O += P V
#pragma unroll
    for (int kk = 0; kk < 2; ++kk) {
      bf16x8 pf = *(const bf16x8*)&pS[w][llo * 72 + kk * 32 + lhi * 8];
#pragma unroll
      for (int nb = 0; nb < 4; ++nb) {
        int vrow = nb * 16 + llo;
        bf16x8 vf = *(const bf16x8*)&vS[vrow * 64 + ((kk * 4 + lhi) ^ (vrow & 7)) * 8];
        oacc[nb] = mfma16(pf, vf, oacc[nb]);
      }
    }
  }
  // epilogue: vals[b, tok, h*64+dk] bf16
  const int b = head >> 4, h = head & 15;
#pragma unroll
  for (int r = 0; r < 4; ++r) {
    float inv = 1.f / lrow[r];
    int tok = qbase + w * 16 + lhi * 4 + r;
#pragma unroll
    for (int nb = 0; nb < 4; ++nb)
      valsb[((size_t)b * 2048 + tok) * 1024 + h * 64 + nb * 16 + llo] =
          (bf16_t)(oacc[nb][r] * inv);
  }
}

// ----------------------------------------------------------------
extern "C" void kernel_launch(void* const* d_in, const int* in_sizes, int n_in,
                              void* d_out, int out_size, void* d_ws, size_t ws_size,
                              hipStream_t stream) {
  const float* x = (const float*)d_in[0];
  const float* wq = (const float*)d_in[1];
  const float* wk = (const float*)d_in[2];
  const float* wv = (const float*)d_in[3];
  const float* wo = (const float*)d_in[4];
  float* out = (float*)d_out;
  float* outK = out + 8388608;
  float* outV = out + 16777216;
  bf16_t* xb = (bf16_t*)d_ws;          // 8388608 elems
  bf16_t* wqb = xb + 8388608;          // 1048576
  bf16_t* wkb = wqb + 1048576;
  bf16_t* wvb = wkb + 1048576;
  bf16_t* wob = wvb + 1048576;
  bf16_t* Qb = wob + 1048576;          // [b,h,t,d] 8388608
  bf16_t* Kb = Qb + 8388608;           // [b,h,t,d]
  bf16_t* vTb = Kb + 8388608;          // [b,h,d,t]
  bf16_t* valsb = vTb + 8388608;       // [b,t,h*64+d]  (total ws use: 92274688 B)
  cast_kernel<<<12288, 256, 0, stream>>>(x, wq, wk, wv, wo, xb, wqb, wkb, wvb, wob);
  gemm_qkv<<<dim3(64, 8, 3), 256, 0, stream>>>(xb, wqb, wkb, wvb, Qb, Kb, vTb, outK, outV);
  attn_kernel<<<dim3(32, 64), 256, 0, stream>>>(Qb, Kb, vTb, valsb);
  gemm_out<<<dim3(64, 8), 256, 0, stream>>>(valsb, wob, out);
}

// Round 2
// 207.147 us; speedup vs baseline: 1.6446x; 1.6446x over previous
//
#include <hip/hip_runtime.h>
#include <hip/hip_bf16.h>

typedef __bf16 bf16_t;
typedef __bf16 bf16x8 __attribute__((ext_vector_type(8)));
typedef __bf16 bf16x4 __attribute__((ext_vector_type(4)));
typedef float f32x4 __attribute__((ext_vector_type(4)));
typedef float f32x16 __attribute__((ext_vector_type(16)));
typedef int i32x4 __attribute__((ext_vector_type(4)));

#define LDS_AS __attribute__((address_space(3)))
#define GLB_AS __attribute__((address_space(1)))

__device__ __forceinline__ void gload_lds16(const void* g, void* l) {
  __builtin_amdgcn_global_load_lds((const GLB_AS void*)g, (LDS_AS void*)l, 16, 0, 0);
}

static __device__ __forceinline__ f32x4 mfma16(bf16x8 a, bf16x8 b, f32x4 c) {
  return __builtin_amdgcn_mfma_f32_16x16x32_bf16(a, b, c, 0, 0, 0);
}
static __device__ __forceinline__ f32x16 mfma32(bf16x8 a, bf16x8 b, f32x16 c) {
  return __builtin_amdgcn_mfma_f32_32x32x16_bf16(a, b, c, 0, 0, 0);
}
__device__ __forceinline__ int cvtpk_bf16(float lo, float hi) {
  int r;
  asm("v_cvt_pk_bf16_f32 %0, %1, %2" : "=v"(r) : "v"(lo), "v"(hi));
  return r;
}
__device__ __forceinline__ bf16x8 mkfrag(int w0, int w1, int w2, int w3) {
  i32x4 v;
  v[0] = w0; v[1] = w1; v[2] = w2; v[3] = w3;
  return __builtin_bit_cast(bf16x8, v);
}

// 0.125 (1/sqrt(dk)) * log2(e): folds softmax base-2 conversion into the Q scale.
#define QSCALE 0.18033688011112042f

// ---------------------------------------------------------------- cast fp32 -> bf16
__global__ __launch_bounds__(256) void cast_kernel(
    const float* __restrict__ x, const float* __restrict__ wq,
    const float* __restrict__ wk, const float* __restrict__ wv,
    const float* __restrict__ wo, bf16_t* __restrict__ xb,
    bf16_t* __restrict__ wqb, bf16_t* __restrict__ wkb,
    bf16_t* __restrict__ wvb, bf16_t* __restrict__ wob) {
  size_t i = ((size_t)blockIdx.x * 256 + threadIdx.x) * 4;
  const float* s;
  bf16_t* d;
  size_t off;
  if (i < 8388608) {
    s = x; d = xb; off = i;
  } else {
    size_t j = i - 8388608;
    int wi = (int)(j >> 20);
    off = j & 1048575;
    s = wi == 0 ? wq : wi == 1 ? wk : wi == 2 ? wv : wo;
    d = wi == 0 ? wqb : wi == 1 ? wkb : wi == 2 ? wvb : wob;
  }
  float4 v = *(const float4*)(s + off);
  bf16x4 o;
  o[0] = (bf16_t)v.x; o[1] = (bf16_t)v.y; o[2] = (bf16_t)v.z; o[3] = (bf16_t)v.w;
  *(bf16x4*)(d + off) = o;
}

// ---------------------------------------------------------------- GEMM mainloop (m97 structure)
__device__ __forceinline__ void gemm_loop(const bf16_t* __restrict__ A,
                                          const bf16_t* __restrict__ W,
                                          bf16_t* lA, bf16_t* lB, int rowBase,
                                          int colBase, int tid,
                                          f32x4 (&acc)[4][4]) {
  const int lane = tid & 63, w = tid >> 6;
  const int lhi = lane >> 4, llo = lane & 15;
  const int wr = w >> 1, wc = w & 1;
  const int cBase = w * 64 + lane;
  for (int kt = 0; kt < 32; ++kt) {
    __syncthreads();
#pragma unroll
    for (int i = 0; i < 2; ++i) {
      int c = i * 256 + cBase;
      gload_lds16(A + (size_t)(rowBase + (c >> 2)) * 1024 + kt * 32 + (c & 3) * 8,
                  lA + (size_t)(i * 256 + w * 64) * 8);
      gload_lds16(W + (size_t)(colBase + (c >> 2)) * 1024 + kt * 32 + (c & 3) * 8,
                  lB + (size_t)(i * 256 + w * 64) * 8);
    }
    __syncthreads();
    bf16x8 aF[4], bF[4];
#pragma unroll
    for (int i = 0; i < 4; ++i)
      aF[i] = *(const bf16x8*)&lA[(wr * 64 + i * 16 + llo) * 32 + lhi * 8];
#pragma unroll
    for (int j = 0; j < 4; ++j)
      bF[j] = *(const bf16x8*)&lB[(wc * 64 + j * 16 + llo) * 32 + lhi * 8];
#pragma unroll
    for (int i = 0; i < 4; ++i)
#pragma unroll
      for (int j = 0; j < 4; ++j) acc[i][j] = mfma16(aF[i], bF[j], acc[i][j]);
  }
}

// ---------------------------------------------------------------- QKV projection
__global__ __launch_bounds__(256) void gemm_qkv(
    const bf16_t* __restrict__ xb, const bf16_t* __restrict__ wqb,
    const bf16_t* __restrict__ wkb, const bf16_t* __restrict__ wvb,
    bf16_t* __restrict__ Qb, bf16_t* __restrict__ Kb, bf16_t* __restrict__ vTb,
    float* __restrict__ outK, float* __restrict__ outV) {
  __shared__ bf16_t lA[128 * 32];
  __shared__ bf16_t lB[128 * 32];
  const int tid = threadIdx.x;
  const int mode = blockIdx.z;
  const bf16_t* W = mode == 0 ? wqb : (mode == 1 ? wkb : wvb);
  const int rowBase = blockIdx.x * 128, colBase = blockIdx.y * 128;
  f32x4 acc[4][4] = {};
  gemm_loop(xb, W, lA, lB, rowBase, colBase, tid, acc);
  const int lane = tid & 63, w = tid >> 6;
  const int lhi = lane >> 4, llo = lane & 15;
  const int wr = w >> 1, wc = w & 1;
#pragma unroll
  for (int i = 0; i < 4; ++i) {
    int m0 = rowBase + wr * 64 + i * 16 + lhi * 4;
    int b = m0 >> 11;
    int tok0 = m0 & 2047;
#pragma unroll
    for (int j = 0; j < 4; ++j) {
      int n = colBase + wc * 64 + j * 16 + llo;
      int h = n >> 6, dk = n & 63;
      size_t hoff = ((size_t)(b * 16 + h) * 2048 + tok0) * 64 + dk;
      if (mode == 0) {
        // pre-scaled Q (1/8 * log2e) so attention softmax runs in exp2 domain
#pragma unroll
        for (int r = 0; r < 4; ++r)
          Qb[hoff + (size_t)r * 64] = (bf16_t)(acc[i][j][r] * QSCALE);
      } else if (mode == 1) {
#pragma unroll
        for (int r = 0; r < 4; ++r) {
          outK[hoff + (size_t)r * 64] = acc[i][j][r];
          Kb[hoff + (size_t)r * 64] = (bf16_t)acc[i][j][r];
        }
      } else {
#pragma unroll
        for (int r = 0; r < 4; ++r) outV[hoff + (size_t)r * 64] = acc[i][j][r];
        bf16x4 pk;
#pragma unroll
        for (int r = 0; r < 4; ++r) pk[r] = (bf16_t)acc[i][j][r];
        *(bf16x4*)&vTb[((size_t)(b * 16 + h) * 64 + dk) * 2048 + tok0] = pk;
      }
    }
  }
}

// ---------------------------------------------------------------- output projection
__global__ __launch_bounds__(256) void gemm_out(const bf16_t* __restrict__ valsb,
                                                const bf16_t* __restrict__ wob,
                                                float* __restrict__ out) {
  __shared__ bf16_t lA[128 * 32];
  __shared__ bf16_t lB[128 * 32];
  const int tid = threadIdx.x;
  const int rowBase = blockIdx.x * 128, colBase = blockIdx.y * 128;
  f32x4 acc[4][4] = {};
  gemm_loop(valsb, wob, lA, lB, rowBase, colBase, tid, acc);
  const int lane = tid & 63, w = tid >> 6;
  const int lhi = lane >> 4, llo = lane & 15;
  const int wr = w >> 1, wc = w & 1;
#pragma unroll
  for (int i = 0; i < 4; ++i) {
    int m0 = rowBase + wr * 64 + i * 16 + lhi * 4;
#pragma unroll
    for (int j = 0; j < 4; ++j) {
      int n = colBase + wc * 64 + j * 16 + llo;
#pragma unroll
      for (int r = 0; r < 4; ++r) out[(size_t)(m0 + r) * 1024 + n] = acc[i][j][r];
    }
  }
}

// ---------------------------------------------------------------- flash attention (causal)
// 8-wave 32x32 structure (m214 ladder): wave owns 32 q-rows, KVBLK=64.
// Swapped QK^T: S^T = mfma32(Kfrag, Qfrag) -> lane holds full P-row (32 k-vals)
// for q = lane&31; softmax in-register (1 shfl per reduce). PV computes
// O^T = mfma32(V^Tfrag, P^Tfrag) so m/l stats stay lane-local.
// K/V LDS tiles XOR-swizzled via pre-swizzled global source (rule 21).
__global__ __launch_bounds__(512) void attn_kernel(const bf16_t* __restrict__ Qb,
                                                   const bf16_t* __restrict__ Kb,
                                                   const bf16_t* __restrict__ vTb,
                                                   bf16_t* __restrict__ valsb) {
  __shared__ bf16_t kS[2][64 * 64];
  __shared__ bf16_t vS[2][64 * 64];
  const int tid = threadIdx.x;
  const int w = tid >> 6, lane = tid & 63;
  const int ql = lane & 31, hi = lane >> 5, hi4 = hi * 4;
  const int head = blockIdx.x;
  const int qb = 7 - blockIdx.y;  // heavy blocks dispatch first (causal balance)
  const int qbase = qb * 256;
  const int qw = qbase + w * 32;  // wave's first q row
  const int qrow = qw + ql;       // lane's q row
  const int nkt = qb * 4 + 4;
  const bf16_t* Qh = Qb + (size_t)head * 131072;
  const bf16_t* Kh = Kb + (size_t)head * 131072;
  const bf16_t* Vh = vTb + (size_t)head * 131072;

  // Q B-frags in registers: B[dk][q], lane: q=ql, dk = kk*16 + hi*8 + i
  bf16x8 qB[4];
#pragma unroll
  for (int kk = 0; kk < 4; ++kk)
    qB[kk] = *(const bf16x8*)&Qh[(size_t)qrow * 64 + kk * 16 + hi * 8];

  f32x16 oacc0 = {}, oacc1 = {};  // O^T[d in 0..31 / 32..63][q=ql]
  float mrow = -__builtin_inff(), lrow = 0.f;

  const int srow = tid >> 3;                 // staged row 0..63
  const int ssrc = (tid & 7) ^ (srow & 7);   // pre-swizzled source chunk
  const int ldst = w * 512;                  // wave-uniform LDS elem offset

  auto STAGE = [&](int kt_, int bi) {
    const int kb_ = kt_ * 64;
    gload_lds16(Kh + (size_t)(kb_ + srow) * 64 + ssrc * 8, &kS[bi][ldst]);
    gload_lds16(Vh + (size_t)srow * 2048 + kb_ + ssrc * 8, &vS[bi][ldst]);
  };

  STAGE(0, 0);
  __syncthreads();
  int cur = 0;
  for (int kt = 0; kt < nkt; ++kt) {
    const int kbase = kt * 64;
    if (kt + 1 < nkt) STAGE(kt + 1, cur ^ 1);  // prefetch in flight during compute
    if (kbase <= qw) {                         // wave-uniform causal skip
      const bf16_t* kb = kS[cur];
      const bf16_t* vb = vS[cur];
      const int sw0 = ql & 7;
      f32x16 st0 = {}, st1 = {};
      __builtin_amdgcn_s_setprio(1);
#pragma unroll
      for (int kk = 0; kk < 4; ++kk) {
        bf16x8 kf0 = *(const bf16x8*)&kb[ql * 64 + (((kk * 2 + hi) ^ sw0) * 8)];
        st0 = mfma32(kf0, qB[kk], st0);
      }
#pragma unroll
      for (int kk = 0; kk < 4; ++kk) {
        bf16x8 kf1 = *(const bf16x8*)&kb[(32 + ql) * 64 + (((kk * 2 + hi) ^ sw0) * 8)];
        st1 = mfma32(kf1, qB[kk], st1);
      }
      __builtin_amdgcn_s_setprio(0);
      // causal mask: only the wave's diagonal tile
      if (kbase + 64 > qw) {
#pragma unroll
        for (int rg = 0; rg < 16; ++rg) {
          const int kof = (rg & 3) + 8 * (rg >> 2) + hi4;
          if (kbase + kof > qrow) st0[rg] = -__builtin_inff();
          if (kbase + 32 + kof > qrow) st1[rg] = -__builtin_inff();
        }
      }
      // row max: in-lane tree + one xor-32 shuffle
      float mx[8];
#pragma unroll
      for (int j = 0; j < 8; ++j)
        mx[j] = fmaxf(fmaxf(st0[j], st0[j + 8]), fmaxf(st1[j], st1[j + 8]));
#pragma unroll
      for (int j = 0; j < 4; ++j) mx[j] = fmaxf(mx[j], mx[j + 4]);
      float tm = fmaxf(fmaxf(mx[0], mx[1]), fmaxf(mx[2], mx[3]));
      tm = fmaxf(tm, __shfl_xor(tm, 32));
      if (tm > mrow + 8.f) {  // defer-max (T13): rescale only on >2^8 growth
        const float corr = exp2f(mrow - tm);
        mrow = tm;
        lrow *= corr;
#pragma unroll
        for (int rg = 0; rg < 16; ++rg) {
          oacc0[rg] *= corr;
          oacc1[rg] *= corr;
        }
      }
      float r0 = 0.f, r1 = 0.f, r2 = 0.f, r3 = 0.f;
#pragma unroll
      for (int rg = 0; rg < 16; rg += 4) {
        st0[rg] = exp2f(st0[rg] - mrow);         r0 += st0[rg];
        st0[rg + 1] = exp2f(st0[rg + 1] - mrow); r1 += st0[rg + 1];
        st0[rg + 2] = exp2f(st0[rg + 2] - mrow); r2 += st0[rg + 2];
        st0[rg + 3] = exp2f(st0[rg + 3] - mrow); r3 += st0[rg + 3];
        st1[rg] = exp2f(st1[rg] - mrow);         r0 += st1[rg];
        st1[rg + 1] = exp2f(st1[rg + 1] - mrow); r1 += st1[rg + 1];
        st1[rg + 2] = exp2f(st1[rg + 2] - mrow); r2 += st1[rg + 2];
        st1[rg + 3] = exp2f(st1[rg + 3] - mrow); r3 += st1[rg + 3];
      }
      float rs = (r0 + r1) + (r2 + r3);
      rs += __shfl_xor(rs, 32);
      lrow += rs;
      // P -> bf16 B-frags: cvt_pk pairs + permlane32_swap (T12)
      int a0 = cvtpk_bf16(st0[0], st0[1]), a1 = cvtpk_bf16(st0[2], st0[3]);
      int a2 = cvtpk_bf16(st0[4], st0[5]), a3 = cvtpk_bf16(st0[6], st0[7]);
      int a4 = cvtpk_bf16(st0[8], st0[9]), a5 = cvtpk_bf16(st0[10], st0[11]);
      int a6 = cvtpk_bf16(st0[12], st0[13]), a7 = cvtpk_bf16(st0[14], st0[15]);
      int b0 = cvtpk_bf16(st1[0], st1[1]), b1 = cvtpk_bf16(st1[2], st1[3]);
      int b2 = cvtpk_bf16(st1[4], st1[5]), b3 = cvtpk_bf16(st1[6], st1[7]);
      int b4 = cvtpk_bf16(st1[8], st1[9]), b5 = cvtpk_bf16(st1[10], st1[11]);
      int b6 = cvtpk_bf16(st1[12], st1[13]), b7 = cvtpk_bf16(st1[14], st1[15]);
      auto s02 = __builtin_amdgcn_permlane32_swap(a0, a2, false, false);
      auto s13 = __builtin_amdgcn_permlane32_swap(a1, a3, false, false);
      auto s46 = __builtin_amdgcn_permlane32_swap(a4, a6, false, false);
      auto s57 = __builtin_amdgcn_permlane32_swap(a5, a7, false, false);
      auto t02 = __builtin_amdgcn_permlane32_swap(b0, b2, false, false);
      auto t13 = __builtin_amdgcn_permlane32_swap(b1, b3, false, false);
      auto t46 = __builtin_amdgcn_permlane32_swap(b4, b6, false, false);
      auto t57 = __builtin_amdgcn_permlane32_swap(b5, b7, false, false);
      bf16x8 pB0 = mkfrag(s02[0], s13[0], s02[1], s13[1]);
      bf16x8 pB1 = mkfrag(s46[0], s57[0], s46[1], s57[1]);
      bf16x8 pB2 = mkfrag(t02[0], t13[0], t02[1], t13[1]);
      bf16x8 pB3 = mkfrag(t46[0], t57[0], t46[1], t57[1]);
      // O^T += V^T · P^T
      __builtin_amdgcn_s_setprio(1);
#pragma unroll
      for (int ks = 0; ks < 4; ++ks) {
        bf16x8 pb = ks == 0 ? pB0 : ks == 1 ? pB1 : ks == 2 ? pB2 : pB3;
        bf16x8 vf0 = *(const bf16x8*)&vb[ql * 64 + (((ks * 2 + hi) ^ sw0) * 8)];
        oacc0 = mfma32(vf0, pb, oacc0);
        bf16x8 vf1 = *(const bf16x8*)&vb[(32 + ql) * 64 + (((ks * 2 + hi) ^ sw0) * 8)];
        oacc1 = mfma32(vf1, pb, oacc1);
      }
      __builtin_amdgcn_s_setprio(0);
    }
    __syncthreads();
    cur ^= 1;
  }
  // epilogue: vals[b, tok=qrow, h*64 + d], d = 32*td + 8*rg + 4*hi + j
  const float inv = 1.f / lrow;
  size_t base = ((size_t)(head >> 4) * 2048 + qrow) * 1024 + (head & 15) * 64 + hi4;
#pragma unroll
  for (int rg = 0; rg < 4; ++rg) {
    bf16x4 o0, o1;
#pragma unroll
    for (int j = 0; j < 4; ++j) {
      o0[j] = (bf16_t)(oacc0[rg * 4 + j] * inv);
      o1[j] = (bf16_t)(oacc1[rg * 4 + j] * inv);
    }
    *(bf16x4*)&valsb[base + rg * 8] = o0;
    *(bf16x4*)&valsb[base + 32 + rg * 8] = o1;
  }
}

// ----------------------------------------------------------------
extern "C" void kernel_launch(void* const* d_in, const int* in_sizes, int n_in,
                              void* d_out, int out_size, void* d_ws, size_t ws_size,
                              hipStream_t stream) {
  const float* x = (const float*)d_in[0];
  const float* wq = (const float*)d_in[1];
  const float* wk = (const float*)d_in[2];
  const float* wv = (const float*)d_in[3];
  const float* wo = (const float*)d_in[4];
  float* out = (float*)d_out;
  float* outK = out + 8388608;
  float* outV = out + 16777216;
  bf16_t* xb = (bf16_t*)d_ws;
  bf16_t* wqb = xb + 8388608;
  bf16_t* wkb = wqb + 1048576;
  bf16_t* wvb = wkb + 1048576;
  bf16_t* wob = wvb + 1048576;
  bf16_t* Qb = wob + 1048576;     // [b,h,t,d] pre-scaled by QSCALE
  bf16_t* Kb = Qb + 8388608;      // [b,h,t,d]
  bf16_t* vTb = Kb + 8388608;     // [b,h,d,t]
  bf16_t* valsb = vTb + 8388608;  // [b,t,1024]
  cast_kernel<<<12288, 256, 0, stream>>>(x, wq, wk, wv, wo, xb, wqb, wkb, wvb, wob);
  gemm_qkv<<<dim3(64, 8, 3), 256, 0, stream>>>(xb, wqb, wkb, wvb, Qb, Kb, vTb, outK, outV);
  attn_kernel<<<dim3(64, 8), 512, 0, stream>>>(Qb, Kb, vTb, valsb);
  gemm_out<<<dim3(64, 8), 256, 0, stream>>>(valsb, wob, out);
}

// Round 3
// 188.149 us; speedup vs baseline: 1.8107x; 1.1010x over previous
//
#include <hip/hip_runtime.h>
#include <hip/hip_bf16.h>

typedef __bf16 bf16_t;
typedef __bf16 bf16x8 __attribute__((ext_vector_type(8)));
typedef __bf16 bf16x4 __attribute__((ext_vector_type(4)));
typedef float f32x4 __attribute__((ext_vector_type(4)));
typedef float f32x16 __attribute__((ext_vector_type(16)));
typedef int i32x4 __attribute__((ext_vector_type(4)));

#define LDS_AS __attribute__((address_space(3)))
#define GLB_AS __attribute__((address_space(1)))

__device__ __forceinline__ void gload_lds16(const void* g, void* l) {
  __builtin_amdgcn_global_load_lds((const GLB_AS void*)g, (LDS_AS void*)l, 16, 0, 0);
}

static __device__ __forceinline__ f32x4 mfma16(bf16x8 a, bf16x8 b, f32x4 c) {
  return __builtin_amdgcn_mfma_f32_16x16x32_bf16(a, b, c, 0, 0, 0);
}
static __device__ __forceinline__ f32x16 mfma32(bf16x8 a, bf16x8 b, f32x16 c) {
  return __builtin_amdgcn_mfma_f32_32x32x16_bf16(a, b, c, 0, 0, 0);
}
__device__ __forceinline__ int cvtpk_bf16(float lo, float hi) {
  int r;
  asm("v_cvt_pk_bf16_f32 %0, %1, %2" : "=v"(r) : "v"(lo), "v"(hi));
  return r;
}
__device__ __forceinline__ bf16x8 mkfrag(int w0, int w1, int w2, int w3) {
  i32x4 v;
  v[0] = w0; v[1] = w1; v[2] = w2; v[3] = w3;
  return __builtin_bit_cast(bf16x8, v);
}

// barrier helpers: vmcnt BEFORE s_barrier (cross-thread staging landed),
// memory-clobber asm + sched_barrier(0) pin ds_reads below the barrier.
#define PIPE_WAIT_BARRIER(N)                                   \
  asm volatile("s_waitcnt vmcnt(" #N ")" ::: "memory");        \
  __builtin_amdgcn_s_barrier();                                \
  asm volatile("" ::: "memory");                               \
  __builtin_amdgcn_sched_barrier(0)

#define PIPE_END_BARRIER()                                     \
  __builtin_amdgcn_s_barrier();                                \
  asm volatile("" ::: "memory");                               \
  __builtin_amdgcn_sched_barrier(0)

// 0.125 (1/sqrt(dk)) * log2(e): folds softmax base-2 conversion into the Q scale.
#define QSCALE 0.18033688011112042f

// ---------------------------------------------------------------- cast fp32 -> bf16
__global__ __launch_bounds__(256) void cast_kernel(
    const float* __restrict__ x, const float* __restrict__ wq,
    const float* __restrict__ wk, const float* __restrict__ wv,
    const float* __restrict__ wo, bf16_t* __restrict__ xb,
    bf16_t* __restrict__ wqb, bf16_t* __restrict__ wkb,
    bf16_t* __restrict__ wvb, bf16_t* __restrict__ wob) {
  size_t i = ((size_t)blockIdx.x * 256 + threadIdx.x) * 4;
  const float* s;
  bf16_t* d;
  size_t off;
  if (i < 8388608) {
    s = x; d = xb; off = i;
  } else {
    size_t j = i - 8388608;
    int wi = (int)(j >> 20);
    off = j & 1048575;
    s = wi == 0 ? wq : wi == 1 ? wk : wi == 2 ? wv : wo;
    d = wi == 0 ? wqb : wi == 1 ? wkb : wi == 2 ? wvb : wob;
  }
  float4 v = *(const float4*)(s + off);
  bf16x4 o;
  o[0] = (bf16_t)v.x; o[1] = (bf16_t)v.y; o[2] = (bf16_t)v.z; o[3] = (bf16_t)v.w;
  *(bf16x4*)(d + off) = o;
}

// ---------------------------------------------------------------- fused QKV GEMM
// Block: 128 rows x (128 cols x 3 matrices). 512 thr = 8 waves (2M x 4N),
// wave-tile 64x96. BK=32, LDS dbuf 2x[A 128x32 | B 384x32] = 64KB.
// Pipeline: STAGE(t+1) -> vmcnt(4) -> barrier -> ds_read+MFMA -> barrier (T3/T4).
// XOR swizzle (slot^row&3) via pre-swizzled global source (rule 21).
__global__ __launch_bounds__(512) void gemm_qkv(
    const bf16_t* __restrict__ xb, const bf16_t* __restrict__ wqb,
    const bf16_t* __restrict__ wkb, const bf16_t* __restrict__ wvb,
    bf16_t* __restrict__ Qb, bf16_t* __restrict__ Kb, bf16_t* __restrict__ vTb,
    float* __restrict__ outK, float* __restrict__ outV) {
  __shared__ __align__(16) bf16_t lds[32768];  // 2 bufs x 16384 elems
  const int tid = threadIdx.x;
  const int lane = tid & 63, w = tid >> 6;
  const int llo = lane & 15, lhi = lane >> 4;
  const int wm = w >> 2, wn = w & 3;
  const int rowBase = blockIdx.x * 128, colW = blockIdx.y * 128;

  // staging sources: A 1 chunk/thread, B 3 chunks (load i from matrix i)
  const int arow = tid >> 2, asrc = (tid & 3) ^ (arow & 3);
  const bf16_t* srcA = xb + (size_t)(rowBase + arow) * 1024 + asrc * 8;
  const bf16_t* srcB0 = wqb + (size_t)(colW + arow) * 1024 + asrc * 8;
  const bf16_t* srcB1 = wkb + (size_t)(colW + arow) * 1024 + asrc * 8;
  const bf16_t* srcB2 = wvb + (size_t)(colW + arow) * 1024 + asrc * 8;
  const int dstA = tid * 8;
  const int dstB0 = 4096 + tid * 8;
  const int dstB1 = 4096 + (512 + tid) * 8;
  const int dstB2 = 4096 + (1024 + tid) * 8;

  auto STAGE = [&](int kt, int b) {
    bf16_t* base = lds + b * 16384;
    gload_lds16(srcA + kt * 32, base + dstA);
    gload_lds16(srcB0 + kt * 32, base + dstB0);
    gload_lds16(srcB1 + kt * 32, base + dstB1);
    gload_lds16(srcB2 + kt * 32, base + dstB2);
  };

  f32x4 acc[4][6] = {};
  const int xr = llo & 3;
  STAGE(0, 0);
  for (int kt = 0; kt < 32; ++kt) {
    if (kt + 1 < 32) {
      STAGE(kt + 1, (kt + 1) & 1);
      PIPE_WAIT_BARRIER(4);
    } else {
      PIPE_WAIT_BARRIER(0);
    }
    const bf16_t* bufA = lds + (kt & 1) * 16384;
    const bf16_t* bufB = bufA + 4096;
    bf16x8 aF[4], bF[6];
#pragma unroll
    for (int mf = 0; mf < 4; ++mf)
      aF[mf] = *(const bf16x8*)&bufA[(wm * 64 + mf * 16 + llo) * 32 +
                                     ((lhi ^ xr) * 8)];
#pragma unroll
    for (int nf = 0; nf < 6; ++nf)
      bF[nf] = *(const bf16x8*)&bufB[(wn * 96 + nf * 16 + llo) * 32 +
                                     ((lhi ^ xr) * 8)];
    __builtin_amdgcn_s_setprio(1);
#pragma unroll
    for (int mf = 0; mf < 4; ++mf)
#pragma unroll
      for (int nf = 0; nf < 6; ++nf) acc[mf][nf] = mfma16(aF[mf], bF[nf], acc[mf][nf]);
    __builtin_amdgcn_s_setprio(0);
    PIPE_END_BARRIER();
  }

  // epilogue: frag (mf,nf) -> rows m0..m0+3, fused col n = wn*96+nf*16+llo
#pragma unroll
  for (int mf = 0; mf < 4; ++mf) {
    int m0 = rowBase + wm * 64 + mf * 16 + lhi * 4;
    int b = m0 >> 11, tok0 = m0 & 2047;
#pragma unroll
    for (int nf = 0; nf < 6; ++nf) {
      int n = wn * 96 + nf * 16 + llo;
      int mat = n >> 7;
      int nm = colW + (n & 127);
      int h = nm >> 6, dk = nm & 63;
      size_t hoff = ((size_t)(b * 16 + h) * 2048 + tok0) * 64 + dk;
      if (mat == 0) {
#pragma unroll
        for (int r = 0; r < 4; ++r)
          Qb[hoff + (size_t)r * 64] = (bf16_t)(acc[mf][nf][r] * QSCALE);
      } else if (mat == 1) {
#pragma unroll
        for (int r = 0; r < 4; ++r) {
          outK[hoff + (size_t)r * 64] = acc[mf][nf][r];
          Kb[hoff + (size_t)r * 64] = (bf16_t)acc[mf][nf][r];
        }
      } else {
#pragma unroll
        for (int r = 0; r < 4; ++r) outV[hoff + (size_t)r * 64] = acc[mf][nf][r];
        bf16x4 pk;
#pragma unroll
        for (int r = 0; r < 4; ++r) pk[r] = (bf16_t)acc[mf][nf][r];
        *(bf16x4*)&vTb[((size_t)(b * 16 + h) * 64 + dk) * 2048 + tok0] = pk;
      }
    }
  }
}

// ---------------------------------------------------------------- output projection
// 128x128 tile, 4 waves (2x2 of 64x64), BK=32, same T3/T4 pipeline. LDS 32KB.
__global__ __launch_bounds__(256) void gemm_out(const bf16_t* __restrict__ valsb,
                                                const bf16_t* __restrict__ wob,
                                                float* __restrict__ out) {
  __shared__ __align__(16) bf16_t lds[16384];  // 2 bufs x 8192 elems
  const int tid = threadIdx.x;
  const int lane = tid & 63, w = tid >> 6;
  const int llo = lane & 15, lhi = lane >> 4;
  const int wm = w >> 1, wn = w & 1;
  const int rowBase = blockIdx.x * 128, colW = blockIdx.y * 128;

  // staging: A 2 chunks/thread, B 2 chunks/thread
  int g0 = tid, g1 = 256 + tid;
  int r0 = g0 >> 2, r1 = g1 >> 2;
  int s0 = (g0 & 3) ^ (r0 & 3), s1 = (g1 & 3) ^ (r1 & 3);
  const bf16_t* srcA0 = valsb + (size_t)(rowBase + r0) * 1024 + s0 * 8;
  const bf16_t* srcA1 = valsb + (size_t)(rowBase + r1) * 1024 + s1 * 8;
  const bf16_t* srcB0 = wob + (size_t)(colW + r0) * 1024 + s0 * 8;
  const bf16_t* srcB1 = wob + (size_t)(colW + r1) * 1024 + s1 * 8;
  const int dA0 = g0 * 8, dA1 = g1 * 8;
  const int dB0 = 4096 + g0 * 8, dB1 = 4096 + g1 * 8;

  auto STAGE = [&](int kt, int b) {
    bf16_t* base = lds + b * 8192;
    gload_lds16(srcA0 + kt * 32, base + dA0);
    gload_lds16(srcA1 + kt * 32, base + dA1);
    gload_lds16(srcB0 + kt * 32, base + dB0);
    gload_lds16(srcB1 + kt * 32, base + dB1);
  };

  f32x4 acc[4][4] = {};
  const int xr = llo & 3;
  STAGE(0, 0);
  for (int kt = 0; kt < 32; ++kt) {
    if (kt + 1 < 32) {
      STAGE(kt + 1, (kt + 1) & 1);
      PIPE_WAIT_BARRIER(4);
    } else {
      PIPE_WAIT_BARRIER(0);
    }
    const bf16_t* bufA = lds + (kt & 1) * 8192;
    const bf16_t* bufB = bufA + 4096;
    bf16x8 aF[4], bF[4];
#pragma unroll
    for (int mf = 0; mf < 4; ++mf)
      aF[mf] = *(const bf16x8*)&bufA[(wm * 64 + mf * 16 + llo) * 32 +
                                     ((lhi ^ xr) * 8)];
#pragma unroll
    for (int nf = 0; nf < 4; ++nf)
      bF[nf] = *(const bf16x8*)&bufB[(wn * 64 + nf * 16 + llo) * 32 +
                                     ((lhi ^ xr) * 8)];
    __builtin_amdgcn_s_setprio(1);
#pragma unroll
    for (int mf = 0; mf < 4; ++mf)
#pragma unroll
      for (int nf = 0; nf < 4; ++nf) acc[mf][nf] = mfma16(aF[mf], bF[nf], acc[mf][nf]);
    __builtin_amdgcn_s_setprio(0);
    PIPE_END_BARRIER();
  }
#pragma unroll
  for (int mf = 0; mf < 4; ++mf) {
    int m0 = rowBase + wm * 64 + mf * 16 + lhi * 4;
#pragma unroll
    for (int nf = 0; nf < 4; ++nf) {
      int n = colW + wn * 64 + nf * 16 + llo;
#pragma unroll
      for (int r = 0; r < 4; ++r) out[(size_t)(m0 + r) * 1024 + n] = acc[mf][nf][r];
    }
  }
}

// ---------------------------------------------------------------- flash attention (causal)
// 8-wave 32x32 structure; unchanged from round 1 (see round-1 notes).
__global__ __launch_bounds__(512) void attn_kernel(const bf16_t* __restrict__ Qb,
                                                   const bf16_t* __restrict__ Kb,
                                                   const bf16_t* __restrict__ vTb,
                                                   bf16_t* __restrict__ valsb) {
  __shared__ bf16_t kS[2][64 * 64];
  __shared__ bf16_t vS[2][64 * 64];
  const int tid = threadIdx.x;
  const int w = tid >> 6, lane = tid & 63;
  const int ql = lane & 31, hi = lane >> 5, hi4 = hi * 4;
  const int head = blockIdx.x;
  const int qb = 7 - blockIdx.y;  // heavy blocks dispatch first (causal balance)
  const int qbase = qb * 256;
  const int qw = qbase + w * 32;
  const int qrow = qw + ql;
  const int nkt = qb * 4 + 4;
  const bf16_t* Qh = Qb + (size_t)head * 131072;
  const bf16_t* Kh = Kb + (size_t)head * 131072;
  const bf16_t* Vh = vTb + (size_t)head * 131072;

  bf16x8 qB[4];
#pragma unroll
  for (int kk = 0; kk < 4; ++kk)
    qB[kk] = *(const bf16x8*)&Qh[(size_t)qrow * 64 + kk * 16 + hi * 8];

  f32x16 oacc0 = {}, oacc1 = {};
  float mrow = -__builtin_inff(), lrow = 0.f;

  const int srow = tid >> 3;
  const int ssrc = (tid & 7) ^ (srow & 7);
  const int ldst = w * 512;

  auto STAGE = [&](int kt_, int bi) {
    const int kb_ = kt_ * 64;
    gload_lds16(Kh + (size_t)(kb_ + srow) * 64 + ssrc * 8, &kS[bi][ldst]);
    gload_lds16(Vh + (size_t)srow * 2048 + kb_ + ssrc * 8, &vS[bi][ldst]);
  };

  STAGE(0, 0);
  __syncthreads();
  int cur = 0;
  for (int kt = 0; kt < nkt; ++kt) {
    const int kbase = kt * 64;
    if (kt + 1 < nkt) STAGE(kt + 1, cur ^ 1);
    if (kbase <= qw) {
      const bf16_t* kb = kS[cur];
      const bf16_t* vb = vS[cur];
      const int sw0 = ql & 7;
      f32x16 st0 = {}, st1 = {};
      __builtin_amdgcn_s_setprio(1);
#pragma unroll
      for (int kk = 0; kk < 4; ++kk) {
        bf16x8 kf0 = *(const bf16x8*)&kb[ql * 64 + (((kk * 2 + hi) ^ sw0) * 8)];
        st0 = mfma32(kf0, qB[kk], st0);
      }
#pragma unroll
      for (int kk = 0; kk < 4; ++kk) {
        bf16x8 kf1 = *(const bf16x8*)&kb[(32 + ql) * 64 + (((kk * 2 + hi) ^ sw0) * 8)];
        st1 = mfma32(kf1, qB[kk], st1);
      }
      __builtin_amdgcn_s_setprio(0);
      if (kbase + 64 > qw) {
#pragma unroll
        for (int rg = 0; rg < 16; ++rg) {
          const int kof = (rg & 3) + 8 * (rg >> 2) + hi4;
          if (kbase + kof > qrow) st0[rg] = -__builtin_inff();
          if (kbase + 32 + kof > qrow) st1[rg] = -__builtin_inff();
        }
      }
      float mx[8];
#pragma unroll
      for (int j = 0; j < 8; ++j)
        mx[j] = fmaxf(fmaxf(st0[j], st0[j + 8]), fmaxf(st1[j], st1[j + 8]));
#pragma unroll
      for (int j = 0; j < 4; ++j) mx[j] = fmaxf(mx[j], mx[j + 4]);
      float tm = fmaxf(fmaxf(mx[0], mx[1]), fmaxf(mx[2], mx[3]));
      tm = fmaxf(tm, __shfl_xor(tm, 32));
      if (tm > mrow + 8.f) {
        const float corr = exp2f(mrow - tm);
        mrow = tm;
        lrow *= corr;
#pragma unroll
        for (int rg = 0; rg < 16; ++rg) {
          oacc0[rg] *= corr;
          oacc1[rg] *= corr;
        }
      }
      float r0 = 0.f, r1 = 0.f, r2 = 0.f, r3 = 0.f;
#pragma unroll
      for (int rg = 0; rg < 16; rg += 4) {
        st0[rg] = exp2f(st0[rg] - mrow);         r0 += st0[rg];
        st0[rg + 1] = exp2f(st0[rg + 1] - mrow); r1 += st0[rg + 1];
        st0[rg + 2] = exp2f(st0[rg + 2] - mrow); r2 += st0[rg + 2];
        st0[rg + 3] = exp2f(st0[rg + 3] - mrow); r3 += st0[rg + 3];
        st1[rg] = exp2f(st1[rg] - mrow);         r0 += st1[rg];
        st1[rg + 1] = exp2f(st1[rg + 1] - mrow); r1 += st1[rg + 1];
        st1[rg + 2] = exp2f(st1[rg + 2] - mrow); r2 += st1[rg + 2];
        st1[rg + 3] = exp2f(st1[rg + 3] - mrow); r3 += st1[rg + 3];
      }
      float rs = (r0 + r1) + (r2 + r3);
      rs += __shfl_xor(rs, 32);
      lrow += rs;
      int a0 = cvtpk_bf16(st0[0], st0[1]), a1 = cvtpk_bf16(st0[2], st0[3]);
      int a2 = cvtpk_bf16(st0[4], st0[5]), a3 = cvtpk_bf16(st0[6], st0[7]);
      int a4 = cvtpk_bf16(st0[8], st0[9]), a5 = cvtpk_bf16(st0[10], st0[11]);
      int a6 = cvtpk_bf16(st0[12], st0[13]), a7 = cvtpk_bf16(st0[14], st0[15]);
      int b0 = cvtpk_bf16(st1[0], st1[1]), b1 = cvtpk_bf16(st1[2], st1[3]);
      int b2 = cvtpk_bf16(st1[4], st1[5]), b3 = cvtpk_bf16(st1[6], st1[7]);
      int b4 = cvtpk_bf16(st1[8], st1[9]), b5 = cvtpk_bf16(st1[10], st1[11]);
      int b6 = cvtpk_bf16(st1[12], st1[13]), b7 = cvtpk_bf16(st1[14], st1[15]);
      auto s02 = __builtin_amdgcn_permlane32_swap(a0, a2, false, false);
      auto s13 = __builtin_amdgcn_permlane32_swap(a1, a3, false, false);
      auto s46 = __builtin_amdgcn_permlane32_swap(a4, a6, false, false);
      auto s57 = __builtin_amdgcn_permlane32_swap(a5, a7, false, false);
      auto t02 = __builtin_amdgcn_permlane32_swap(b0, b2, false, false);
      auto t13 = __builtin_amdgcn_permlane32_swap(b1, b3, false, false);
      auto t46 = __builtin_amdgcn_permlane32_swap(b4, b6, false, false);
      auto t57 = __builtin_amdgcn_permlane32_swap(b5, b7, false, false);
      bf16x8 pB0 = mkfrag(s02[0], s13[0], s02[1], s13[1]);
      bf16x8 pB1 = mkfrag(s46[0], s57[0], s46[1], s57[1]);
      bf16x8 pB2 = mkfrag(t02[0], t13[0], t02[1], t13[1]);
      bf16x8 pB3 = mkfrag(t46[0], t57[0], t46[1], t57[1]);
      __builtin_amdgcn_s_setprio(1);
#pragma unroll
      for (int ks = 0; ks < 4; ++ks) {
        bf16x8 pb = ks == 0 ? pB0 : ks == 1 ? pB1 : ks == 2 ? pB2 : pB3;
        bf16x8 vf0 = *(const bf16x8*)&vb[ql * 64 + (((ks * 2 + hi) ^ sw0) * 8)];
        oacc0 = mfma32(vf0, pb, oacc0);
        bf16x8 vf1 = *(const bf16x8*)&vb[(32 + ql) * 64 + (((ks * 2 + hi) ^ sw0) * 8)];
        oacc1 = mfma32(vf1, pb, oacc1);
      }
      __builtin_amdgcn_s_setprio(0);
    }
    __syncthreads();
    cur ^= 1;
  }
  const float inv = 1.f / lrow;
  size_t base = ((size_t)(head >> 4) * 2048 + qrow) * 1024 + (head & 15) * 64 + hi4;
#pragma unroll
  for (int rg = 0; rg < 4; ++rg) {
    bf16x4 o0, o1;
#pragma unroll
    for (int j = 0; j < 4; ++j) {
      o0[j] = (bf16_t)(oacc0[rg * 4 + j] * inv);
      o1[j] = (bf16_t)(oacc1[rg * 4 + j] * inv);
    }
    *(bf16x4*)&valsb[base + rg * 8] = o0;
    *(bf16x4*)&valsb[base + 32 + rg * 8] = o1;
  }
}

// ----------------------------------------------------------------
extern "C" void kernel_launch(void* const* d_in, const int* in_sizes, int n_in,
                              void* d_out, int out_size, void* d_ws, size_t ws_size,
                              hipStream_t stream) {
  const float* x = (const float*)d_in[0];
  const float* wq = (const float*)d_in[1];
  const float* wk = (const float*)d_in[2];
  const float* wv = (const float*)d_in[3];
  const float* wo = (const float*)d_in[4];
  float* out = (float*)d_out;
  float* outK = out + 8388608;
  float* outV = out + 16777216;
  bf16_t* xb = (bf16_t*)d_ws;
  bf16_t* wqb = xb + 8388608;
  bf16_t* wkb = wqb + 1048576;
  bf16_t* wvb = wkb + 1048576;
  bf16_t* wob = wvb + 1048576;
  bf16_t* Qb = wob + 1048576;     // [b,h,t,d] pre-scaled by QSCALE
  bf16_t* Kb = Qb + 8388608;      // [b,h,t,d]
  bf16_t* vTb = Kb + 8388608;     // [b,h,d,t]
  bf16_t* valsb = vTb + 8388608;  // [b,t,1024]
  cast_kernel<<<12288, 256, 0, stream>>>(x, wq, wk, wv, wo, xb, wqb, wkb, wvb, wob);
  gemm_qkv<<<dim3(64, 8), 512, 0, stream>>>(xb, wqb, wkb, wvb, Qb, Kb, vTb, outK, outV);
  attn_kernel<<<dim3(64, 8), 512, 0, stream>>>(Qb, Kb, vTb, valsb);
  gemm_out<<<dim3(64, 8), 256, 0, stream>>>(valsb, wob, out);
}